// Round 8
// baseline (177.250 us; speedup 1.0000x reference)
//
#include <hip/hip_runtime.h>
#include <math.h>

// ---- problem constants ----
#define NN      4096   // nodes
#define INF_    512    // in features
#define OUTF    256    // out features
#define NHEAD   4
#define HDIM    64
#define KSPLIT  4

typedef __attribute__((ext_vector_type(8))) short  short8x;
typedef __attribute__((ext_vector_type(4))) float  float4x;
typedef __attribute__((ext_vector_type(2))) float  float2x;

__device__ __forceinline__ unsigned short f2bf(float x) {
    union { float f; unsigned int u; } c; c.f = x;
    unsigned int r = (c.u + 0x7FFFu + ((c.u >> 16) & 1u)) >> 16;
    return (unsigned short)r;
}
// pack 2 fp32 -> 2 bf16 in one dword (RNE, identical to f2bf)
__device__ __forceinline__ unsigned int cvtpk_bf16(float lo, float hi) {
    unsigned int r;
    asm("v_cvt_pk_bf16_f32 %0, %1, %2" : "=v"(r) : "v"(lo), "v"(hi));
    return r;
}
// unpack a bf16 pair (one dword) into float2 {lo, hi}
__device__ __forceinline__ float2x bf2up(unsigned int u) {
    union { unsigned int x; float f; } lo, hi;
    lo.x = u << 16; hi.x = u & 0xFFFF0000u;
    float2x r; r[0] = lo.f; r[1] = hi.f; return r;
}
__device__ __forceinline__ float2x max2(float2x a, float2x b) {
    float2x r; r[0] = fmaxf(a[0], b[0]); r[1] = fmaxf(a[1], b[1]); return r;
}

// ============================================================
// K0: cast feat and W to bf16; init out = bias (for split-K atomics)
// ============================================================
__global__ __launch_bounds__(256) void k_cast(const float* __restrict__ feat,
                                              const float* __restrict__ W,
                                              const float* __restrict__ bias,
                                              unsigned short* __restrict__ featb,
                                              unsigned short* __restrict__ Wb,
                                              float* __restrict__ out) {
    const int b = blockIdx.x;
    const int tid = threadIdx.x;
    if (b >= 2176) {
        // bias-init: rows of out = bias  (1024 blocks x 1024 floats)
        int idx = (b - 2176) * 1024 + tid * 4;
        float4x bv = *(const float4x*)(bias + ((tid * 4) & 255));
        *(float4x*)(out + idx) = bv;
        return;
    }
    const float* src;
    unsigned short* dst;
    int idx;
    if (b < 2048) { src = feat; dst = featb; idx = b * 1024 + tid * 4; }
    else          { src = W;    dst = Wb;    idx = (b - 2048) * 1024 + tid * 4; }
    float4x v = *(const float4x*)(src + idx);
    ushort4 u;
    u.x = f2bf(v[0]); u.y = f2bf(v[1]); u.z = f2bf(v[2]); u.w = f2bf(v[3]);
    *(ushort4*)(dst + idx) = u;
}

// ============================================================
// K1: h = feat @ W^T (bf16 MFMA, 32-row tiles -> 128 blocks)
// epilogue: hT bf16 write + es/ed per-head dots from registers
// -> es + exp tables Bt=exp(ed), Dt=exp(0.2 ed)
// ============================================================
__global__ __launch_bounds__(256) void k_hedge(const unsigned short* __restrict__ featb,
                                               const unsigned short* __restrict__ Wb,
                                               const float* __restrict__ a,
                                               unsigned short* __restrict__ hT,
                                               float* __restrict__ es,
                                               unsigned short* __restrict__ Bt,
                                               unsigned short* __restrict__ Dt) {
    __shared__ __align__(16) unsigned short lds_f[32 * 40];
    __shared__ __align__(16) unsigned short lds_w[256 * 40];
    const int tid  = threadIdx.x;
    const int w    = tid >> 6;
    const int lane = tid & 63;
    const int lidx = lane & 15;
    const int quad = lane >> 4;
    const int i0   = blockIdx.x * 32;
    const int srf  = tid >> 3;          // 0..31
    const int skf  = (tid & 7) * 4;     // 0..28
    const int srw  = tid >> 2;          // 0..63
    const int skw  = (tid & 3) * 8;

    float4x acc[2][4];
    #pragma unroll
    for (int p = 0; p < 2; ++p)
        #pragma unroll
        for (int q = 0; q < 4; ++q)
            acc[p][q] = (float4x){0.f, 0.f, 0.f, 0.f};

    for (int kt = 0; kt < INF_; kt += 32) {
        __syncthreads();
        *(ushort4*)&lds_f[srf * 40 + skf] = *(const ushort4*)&featb[(size_t)(i0 + srf) * INF_ + kt + skf];
        #pragma unroll
        for (int itr = 0; itr < 4; ++itr) {
            int n = itr * 64 + srw;
            *(ushort4*)&lds_w[n * 40 + skw]     = *(const ushort4*)&Wb[(size_t)n * INF_ + kt + skw];
            *(ushort4*)&lds_w[n * 40 + skw + 4] = *(const ushort4*)&Wb[(size_t)n * INF_ + kt + skw + 4];
        }
        __syncthreads();
        short8x af[2], bw[4];
        #pragma unroll
        for (int t = 0; t < 2; ++t)
            af[t] = *(const short8x*)&lds_f[(t * 16 + lidx) * 40 + quad * 8];
        #pragma unroll
        for (int t = 0; t < 4; ++t)
            bw[t] = *(const short8x*)&lds_w[(w * 64 + t * 16 + lidx) * 40 + quad * 8];
        #pragma unroll
        for (int it = 0; it < 2; ++it)
            #pragma unroll
            for (int nt = 0; nt < 4; ++nt)
                acc[it][nt] = __builtin_amdgcn_mfma_f32_16x16x32_bf16(
                    af[it], bw[nt], acc[it][nt], 0, 0, 0);
    }
    // ---- hT write (D layout: col=lane&15 block w*64+nt*16, row=quad*4+r) ----
    #pragma unroll
    for (int it = 0; it < 2; ++it)
        #pragma unroll
        for (int nt = 0; nt < 4; ++nt) {
            int col = w * 64 + nt * 16 + lidx;
            int m0r = i0 + it * 16 + quad * 4;
            uint2 u;
            u.x = cvtpk_bf16(acc[it][nt][0], acc[it][nt][1]);
            u.y = cvtpk_bf16(acc[it][nt][2], acc[it][nt][3]);
            *(uint2*)&hT[(size_t)col * NN + m0r] = u;
        }
    // ---- es/ed epilogue: head = w; col_d = nt*16 + lidx ----
    float asrc[4], adst[4];
    #pragma unroll
    for (int nt = 0; nt < 4; ++nt) {
        asrc[nt] = a[w * 2 * HDIM + nt * 16 + lidx];
        adst[nt] = a[w * 2 * HDIM + HDIM + nt * 16 + lidx];
    }
    #pragma unroll
    for (int it = 0; it < 2; ++it)
        #pragma unroll
        for (int r = 0; r < 4; ++r) {
            float s = 0.f, d = 0.f;
            #pragma unroll
            for (int nt = 0; nt < 4; ++nt) {
                s += acc[it][nt][r] * asrc[nt];
                d += acc[it][nt][r] * adst[nt];
            }
            #pragma unroll
            for (int off = 1; off < 16; off <<= 1) {
                s += __shfl_xor(s, off);
                d += __shfl_xor(d, off);
            }
            if (lidx == 0) {
                int row = i0 + it * 16 + quad * 4 + r;
                es[row * NHEAD + w] = s;
                Bt[row * NHEAD + w] = f2bf(__expf(d));
                Dt[row * NHEAD + w] = f2bf(__expf(0.2f * d));
            }
        }
}

// ============================================================
// K2: den-only pass. 1 row/block, 4096 blocks. Computes den[h]
// via max-trick and writes ONLY the per-row scaled constants
// cA[h] = exp(es)*0.25/den, cC[h] = exp(0.2es)*0.25/den (8 floats).
// No attention matrix materialization.
// ============================================================
__global__ __launch_bounds__(256) void k_den(const float* __restrict__ adj,
                                             const float* __restrict__ es,
                                             const unsigned short* __restrict__ Bt,
                                             const unsigned short* __restrict__ Dt,
                                             float* __restrict__ cden) {
    __shared__ float red[4][4];
    __shared__ float cfs[4];
    const int tid = threadIdx.x;
    const int wv  = tid >> 6;
    const int lane = tid & 63;
    const int i = blockIdx.x;

    const float4x esv = ((const float4x*)es)[i];
    float2x A01, A23, C01, C23;
    A01[0] = __expf(esv[0]); A01[1] = __expf(esv[1]);
    A23[0] = __expf(esv[2]); A23[1] = __expf(esv[3]);
    C01[0] = __expf(0.2f * esv[0]); C01[1] = __expf(0.2f * esv[1]);
    C23[0] = __expf(0.2f * esv[2]); C23[1] = __expf(0.2f * esv[3]);

    const float4x* arow4 = (const float4x*)(adj + (size_t)i * NN);
    const uint4* B4 = (const uint4*)Bt;
    const uint4* D4 = (const uint4*)Dt;

    float2x den01 = (float2x){0.f, 0.f};
    float2x den23 = (float2x){0.f, 0.f};
    #pragma unroll
    for (int t = 0; t < 4; ++t) {
        int jv = t * 256 + tid;
        float4x av = arow4[jv];
        uint4 bu0 = B4[jv * 2], bu1 = B4[jv * 2 + 1];
        uint4 du0 = D4[jv * 2], du1 = D4[jv * 2 + 1];
        unsigned int bwv[8] = {bu0.x, bu0.y, bu0.z, bu0.w, bu1.x, bu1.y, bu1.z, bu1.w};
        unsigned int dwv[8] = {du0.x, du0.y, du0.z, du0.w, du1.x, du1.y, du1.z, du1.w};
        #pragma unroll
        for (int u = 0; u < 4; ++u) {
            float2x b01 = bf2up(bwv[u * 2]);
            float2x b23 = bf2up(bwv[u * 2 + 1]);
            float2x d01 = bf2up(dwv[u * 2]);
            float2x d23 = bf2up(dwv[u * 2 + 1]);
            float mf = (av[u] > 0.1f) ? 1.f : 0.f;
            float2x mf2; mf2[0] = mf; mf2[1] = mf;
            den01 += mf2 * max2(A01 * b01, C01 * d01);
            den23 += mf2 * max2(A23 * b23, C23 * d23);
        }
    }
    float dh[4] = {den01[0], den01[1], den23[0], den23[1]};
    #pragma unroll
    for (int off = 1; off < 64; off <<= 1) {
        #pragma unroll
        for (int h = 0; h < 4; ++h)
            dh[h] += __shfl_xor(dh[h], off);
    }
    if (lane == 0) {
        #pragma unroll
        for (int h = 0; h < 4; ++h) red[wv][h] = dh[h];
    }
    __syncthreads();
    if (tid < 4)
        cfs[tid] = red[0][tid] + red[1][tid] + red[2][tid] + red[3][tid];
    __syncthreads();
    if (tid == 0) {
        float A[4] = {A01[0], A01[1], A23[0], A23[1]};
        float C[4] = {C01[0], C01[1], C23[0], C23[1]};
        float4x cA, cC;
        #pragma unroll
        for (int h = 0; h < 4; ++h) {
            float den = cfs[h];
            float sc = den > 0.f ? 0.25f / den : 0.f;
            cA[h] = A[h] * sc;
            cC[h] = C[h] * sc;
        }
        ((float4x*)cden)[i * 2]     = cA;
        ((float4x*)cden)[i * 2 + 1] = cC;
    }
}

// ============================================================
// K3: fused P-regen + GEMM (out = P @ h, atomicAdd). R7 skeleton:
// LDS-staged B (coalesced, pitch 72), 16 MFMA/wave per barrier
// pair -- but the A-tile (P, 32x64 bf16) is REGENERATED in-register
// per k-step from adj (L3-hot) + tables + per-row cA/cC, instead of
// loading a materialized attn matrix. P-gen VALU (~150 ops) issues
// between barrier and MFMA phase -> overlaps with ds_read/MFMA.
// Grid (128, KSPLIT=4) = 512 blocks, k-slice 1024 = 16 steps.
// ============================================================
__global__ __launch_bounds__(256) void k_fused(const float* __restrict__ adj,
                                               const float* __restrict__ cden,
                                               const unsigned short* __restrict__ Bt,
                                               const unsigned short* __restrict__ Dt,
                                               const unsigned short* __restrict__ hT,
                                               float* __restrict__ out) {
    __shared__ __align__(16) unsigned short lds_p[32 * 72];
    __shared__ __align__(16) unsigned short lds_h[256 * 72];
    const int tid  = threadIdx.x;
    const int w    = tid >> 6;
    const int lane = tid & 63;
    const int lidx = lane & 15;
    const int quad = lane >> 4;
    const int i0    = blockIdx.x * 32;
    const int kbase = blockIdx.y * (NN / KSPLIT);   // 1024-wide k slice
    const int sr   = tid >> 3;          // stage/P row 0..31
    const int sc8  = (tid & 7) * 8;     // stage chunk / P j-offset (shorts)

    // per-row scaled constants for P-regen (row = sr fixed per thread)
    const float4x cAv = ((const float4x*)cden)[(i0 + sr) * 2];
    const float4x cCv = ((const float4x*)cden)[(i0 + sr) * 2 + 1];
    float2x cA01, cA23, cC01, cC23;
    cA01[0] = cAv[0]; cA01[1] = cAv[1]; cA23[0] = cAv[2]; cA23[1] = cAv[3];
    cC01[0] = cCv[0]; cC01[1] = cCv[1]; cC23[0] = cCv[2]; cC23[1] = cCv[3];

    const uint4* B4 = (const uint4*)Bt;   // 16B = 2 j's (8B per j: 4 heads bf16)
    const uint4* D4 = (const uint4*)Dt;

    float4x acc[2][4];
    #pragma unroll
    for (int p = 0; p < 2; ++p)
        #pragma unroll
        for (int q = 0; q < 4; ++q)
            acc[p][q] = (float4x){0.f, 0.f, 0.f, 0.f};

    short8x pb[8];   // B prefetch (hT rows)
    short8x pp;      // P-tile fragment (8 bf16)

    // ---- P-regen for k-step ks into pp ----
    auto COMPP = [&](int ks) {
        const int jb = kbase + ks * 64 + sc8;    // 8 j's
        float4x a0 = *(const float4x*)&adj[(size_t)(i0 + sr) * NN + jb];
        float4x a1 = *(const float4x*)&adj[(size_t)(i0 + sr) * NN + jb + 4];
        uint4 bu0 = B4[jb >> 1], bu1 = B4[(jb >> 1) + 1];
        uint4 bu2 = B4[(jb >> 1) + 2], bu3 = B4[(jb >> 1) + 3];
        uint4 du0 = D4[jb >> 1], du1 = D4[(jb >> 1) + 1];
        uint4 du2 = D4[(jb >> 1) + 2], du3 = D4[(jb >> 1) + 3];
        unsigned int bw[16] = {bu0.x, bu0.y, bu0.z, bu0.w, bu1.x, bu1.y, bu1.z, bu1.w,
                               bu2.x, bu2.y, bu2.z, bu2.w, bu3.x, bu3.y, bu3.z, bu3.w};
        unsigned int dw[16] = {du0.x, du0.y, du0.z, du0.w, du1.x, du1.y, du1.z, du1.w,
                               du2.x, du2.y, du2.z, du2.w, du3.x, du3.y, du3.z, du3.w};
        float pv[8];
        #pragma unroll
        for (int jj = 0; jj < 8; ++jj) {
            float2x b01 = bf2up(bw[jj * 2]);
            float2x b23 = bf2up(bw[jj * 2 + 1]);
            float2x d01 = bf2up(dw[jj * 2]);
            float2x d23 = bf2up(dw[jj * 2 + 1]);
            float2x t01 = max2(cA01 * b01, cC01 * d01);
            float2x t23 = max2(cA23 * b23, cC23 * d23);
            float av = (jj < 4) ? a0[jj] : a1[jj - 4];
            float s = (t01[0] + t01[1]) + (t23[0] + t23[1]);
            pv[jj] = (av > 0.1f) ? s : 0.f;
        }
        union { short8x s; unsigned int u[4]; } pk;
        pk.u[0] = cvtpk_bf16(pv[0], pv[1]);
        pk.u[1] = cvtpk_bf16(pv[2], pv[3]);
        pk.u[2] = cvtpk_bf16(pv[4], pv[5]);
        pk.u[3] = cvtpk_bf16(pv[6], pv[7]);
        pp = pk.s;
    };
    auto LOADB = [&](int ks) {
        const int ko = kbase + ks * 64;
        #pragma unroll
        for (int p = 0; p < 8; ++p)
            pb[p] = *(const short8x*)&hT[(size_t)(p * 32 + sr) * NN + ko + sc8];
    };

    // prologue: step 0
    LOADB(0);
    COMPP(0);

    const int KSTEPS = (NN / KSPLIT) / 64;   // 16
    for (int ks = 0; ks < KSTEPS; ++ks) {
        __syncthreads();
        *(short8x*)&lds_p[sr * 72 + sc8] = pp;
        #pragma unroll
        for (int p = 0; p < 8; ++p)
            *(short8x*)&lds_h[(p * 32 + sr) * 72 + sc8] = pb[p];
        __syncthreads();
        if (ks + 1 < KSTEPS) {
            LOADB(ks + 1);
            COMPP(ks + 1);
        }
        #pragma unroll
        for (int kk = 0; kk < 2; ++kk) {
            short8x af[2], bfr[4];
            #pragma unroll
            for (int it = 0; it < 2; ++it)
                af[it]  = *(const short8x*)&lds_p[(it * 16 + lidx) * 72 + kk * 32 + quad * 8];
            #pragma unroll
            for (int nt = 0; nt < 4; ++nt)
                bfr[nt] = *(const short8x*)&lds_h[(w * 64 + nt * 16 + lidx) * 72 + kk * 32 + quad * 8];
            #pragma unroll
            for (int it = 0; it < 2; ++it)
                #pragma unroll
                for (int nt = 0; nt < 4; ++nt)
                    acc[it][nt] = __builtin_amdgcn_mfma_f32_16x16x32_bf16(
                        af[it], bfr[nt], acc[it][nt], 0, 0, 0);
        }
    }
    #pragma unroll
    for (int it = 0; it < 2; ++it)
        #pragma unroll
        for (int nt = 0; nt < 4; ++nt)
            #pragma unroll
            for (int rr = 0; rr < 4; ++rr) {
                int row = i0 + it * 16 + quad * 4 + rr;
                int col = w * 64 + nt * 16 + lidx;
                unsafeAtomicAdd(&out[(size_t)row * OUTF + col], acc[it][nt][rr]);
            }
}

// ============================================================
extern "C" void kernel_launch(void* const* d_in, const int* in_sizes, int n_in,
                              void* d_out, int out_size, void* d_ws, size_t ws_size,
                              hipStream_t stream) {
    const float* feat = (const float*)d_in[0];   // [4096,512]
    const float* adj  = (const float*)d_in[1];   // [4096,4096]
    const float* W    = (const float*)d_in[2];   // [256,512]
    const float* a    = (const float*)d_in[3];   // [4,128]
    const float* bias = (const float*)d_in[4];   // [256]
    float* out = (float*)d_out;                  // [4096,256] fp32

    char* ws = (char*)d_ws;
    float*          es    = (float*)(ws + 0);                        // 64 KiB
    unsigned short* Btb   = (unsigned short*)(ws + (64u << 10));     // 32 KiB
    unsigned short* Dtb   = (unsigned short*)(ws + (96u << 10));     // 32 KiB
    float*          cden  = (float*)(ws + (128u << 10));             // 128 KiB
    unsigned short* hT    = (unsigned short*)(ws + (256u << 10));    // 2 MiB
    unsigned short* featb = (unsigned short*)(ws + (2560u << 10));   // 4 MiB
    unsigned short* Wb    = (unsigned short*)(ws + (6656u << 10));   // 256 KiB

    k_cast <<<3200,              256, 0, stream>>>(feat, W, bias, featb, Wb, out);
    k_hedge<<<128,               256, 0, stream>>>(featb, Wb, a, hT, es, Btb, Dtb);
    k_den  <<<NN,                256, 0, stream>>>(adj, es, Btb, Dtb, cden);
    k_fused<<<dim3(128, KSPLIT), 256, 0, stream>>>(adj, cden, Btb, Dtb, hT, out);
}